// Round 1
// baseline (3369.160 us; speedup 1.0000x reference)
//
#include <hip/hip_runtime.h>
#include <hip/hip_bf16.h>
#include <cstddef>

#define NNODES 100000
#define NEDGES 1600000
#define NGRAPHS 64

// ---- workspace layout (float offsets); peak concurrent use ~111.4 MB ----
#define WS_H1    0UL          // [N,128] = 12,800,000 floats; reused as AGG1/H2 after gemm1
#define WS_HW1   12800000UL   // [N,96]  = 9,600,000 floats; reused as HW2 after scatter1
#define WS_AGG2  22400000UL   // [N,54]  = 5,400,000 floats
#define WS_HG    27800000UL   // [64,150] = 9,600 floats
#define WS_WT    27809600UL   // folded conv weights, 49,152 floats
#define WS_CB    27858752UL   // folded conv bias, 128 floats

// ---------------------------------------------------------------------------
// Fold BN (eval) into conv weights/bias.
// Wt2 layout: [k][i][m][j] (j=0..3, o = m + 32*j) so the conv kernel can load
// 4 output-channel weights with one float4.
__global__ void prep_weights(const float* __restrict__ conv_w, const float* __restrict__ conv_b,
                             const float* __restrict__ gamma, const float* __restrict__ beta,
                             const float* __restrict__ mean, const float* __restrict__ var,
                             float* __restrict__ Wt, float* __restrict__ bias) {
    int idx = blockIdx.x * 256 + threadIdx.x;
    if (idx < 128) {
        float sc = gamma[idx] * rsqrtf(var[idx] + 1e-5f);
        bias[idx] = (conv_b[idx] - mean[idx]) * sc + beta[idx];
    }
    if (idx < 49152) {
        int j = idx & 3;
        int m = (idx >> 2) & 31;
        int i = (idx >> 7) & 127;
        int k = idx >> 14;
        int o = m + 32 * j;
        float sc = gamma[o] * rsqrtf(var[o] + 1e-5f);
        Wt[idx] = conv_w[o * 384 + i * 3 + k] * sc;
    }
}

// ---------------------------------------------------------------------------
// conv1d(k=3, pad=1) + folded BN + ReLU.  1 wave / block, 16 nodes / block.
// Thread = (node-half h, channel-base m); covers channels {m, m+32, m+64, m+96}.
__global__ __launch_bounds__(64) void conv_bn_relu(
        const float* __restrict__ x, const float* __restrict__ Wt,
        const float* __restrict__ bias, float* __restrict__ h1) {
    __shared__ float xsT[128][20];   // [in-channel][staged row]; rows = n0-1 .. n0+18
    const int lane = threadIdx.x;
    const int n0 = blockIdx.x * 16;

    for (int r = 0; r < 20; ++r) {
        int n = n0 - 1 + r;
        float v0 = 0.f, v1 = 0.f;
        if (n >= 0 && n < NNODES) {
            v0 = x[(size_t)n * 128 + lane];
            v1 = x[(size_t)n * 128 + lane + 64];
        }
        xsT[lane][r] = v0;
        xsT[lane + 64][r] = v1;
    }
    __syncthreads();

    const int h = lane >> 5;
    const int m = lane & 31;
    float acc[4][8];
#pragma unroll
    for (int j = 0; j < 4; ++j)
#pragma unroll
        for (int t = 0; t < 8; ++t) acc[j][t] = 0.f;

    for (int i = 0; i < 128; ++i) {
        const float4 q0 = *(const float4*)&xsT[i][h * 8 + 0];
        const float4 q1 = *(const float4*)&xsT[i][h * 8 + 4];
        const float4 q2 = *(const float4*)&xsT[i][h * 8 + 8];
        float xv[12] = {q0.x, q0.y, q0.z, q0.w, q1.x, q1.y, q1.z, q1.w,
                        q2.x, q2.y, q2.z, q2.w};
#pragma unroll
        for (int k = 0; k < 3; ++k) {
            const float4 wv = *(const float4*)&Wt[(size_t)(k * 128 + i) * 128 + m * 4];
#pragma unroll
            for (int t = 0; t < 8; ++t) {
                float xa = xv[t + k];
                acc[0][t] += xa * wv.x;
                acc[1][t] += xa * wv.y;
                acc[2][t] += xa * wv.z;
                acc[3][t] += xa * wv.w;
            }
        }
    }

    float b0 = bias[m], b1v = bias[m + 32], b2v = bias[m + 64], b3v = bias[m + 96];
#pragma unroll
    for (int t = 0; t < 8; ++t) {
        int n = n0 + h * 8 + t;
        if (n < NNODES) {
            h1[(size_t)n * 128 + m]      = fmaxf(acc[0][t] + b0, 0.f);
            h1[(size_t)n * 128 + m + 32] = fmaxf(acc[1][t] + b1v, 0.f);
            h1[(size_t)n * 128 + m + 64] = fmaxf(acc[2][t] + b2v, 0.f);
            h1[(size_t)n * 128 + m + 96] = fmaxf(acc[3][t] + b3v, 0.f);
        }
    }
}

// ---------------------------------------------------------------------------
// C[M,NOUT] = A[M,K] @ B[K,NOUT]   (no bias; bias added post-aggregation)
// 1 wave / block, 16 rows / block; thread = (row-half h, channel-base m).
template <int K, int NOUT, int J>
__global__ __launch_bounds__(64) void gemm16(
        const float* __restrict__ A, const float* __restrict__ B,
        float* __restrict__ C, int M) {
    __shared__ float xsT[K][20];
    const int lane = threadIdx.x;
    const int n0 = blockIdx.x * 16;

    for (int r = 0; r < 16; ++r) {
        int n = n0 + r;
#pragma unroll
        for (int cc = 0; cc < K; cc += 64) {
            int c = cc + lane;
            if (c < K) xsT[c][r] = (n < M) ? A[(size_t)n * K + c] : 0.f;
        }
    }
    __syncthreads();

    const int h = lane >> 5;
    const int m = lane & 31;
    float acc[J][8];
#pragma unroll
    for (int j = 0; j < J; ++j)
#pragma unroll
        for (int t = 0; t < 8; ++t) acc[j][t] = 0.f;

    for (int i = 0; i < K; ++i) {
        const float4 q0 = *(const float4*)&xsT[i][h * 8 + 0];
        const float4 q1 = *(const float4*)&xsT[i][h * 8 + 4];
        float xv[8] = {q0.x, q0.y, q0.z, q0.w, q1.x, q1.y, q1.z, q1.w};
#pragma unroll
        for (int j = 0; j < J; ++j) {
            int c = m + 32 * j;
            float w = (c < NOUT) ? B[i * NOUT + c] : 0.f;
#pragma unroll
            for (int t = 0; t < 8; ++t) acc[j][t] += xv[t] * w;
        }
    }

#pragma unroll
    for (int j = 0; j < J; ++j) {
        int c = m + 32 * j;
        if (c < NOUT) {
#pragma unroll
            for (int t = 0; t < 8; ++t) {
                int n = n0 + h * 8 + t;
                if (n < M) C[(size_t)n * NOUT + c] = acc[j][t];
            }
        }
    }
}

// ---------------------------------------------------------------------------
// Edge scatter, 96 channels: thread = (edge, 4-channel chunk), 24 chunks/edge.
__global__ void scatter_96(const float* __restrict__ hw, const int* __restrict__ src,
                           const int* __restrict__ dst, const float* __restrict__ ew,
                           float* __restrict__ agg) {
    int gid = blockIdx.x * 256 + threadIdx.x;       // 38,400,000 total (exact)
    int e = gid / 24;
    int p = gid - e * 24;
    int s = src[e], d = dst[e];
    float w = ew[e];
    const float4 v = *(const float4*)(hw + (size_t)s * 96 + p * 4);
    float* o = agg + (size_t)d * 96 + p * 4;
    atomicAdd(o + 0, v.x * w);
    atomicAdd(o + 1, v.y * w);
    atomicAdd(o + 2, v.z * w);
    atomicAdd(o + 3, v.w * w);
}

// Edge scatter, 54 channels: thread = (edge, 2-channel chunk), 27 chunks/edge.
__global__ void scatter_54(const float* __restrict__ hw, const int* __restrict__ src,
                           const int* __restrict__ dst, const float* __restrict__ ew,
                           float* __restrict__ agg) {
    int gid = blockIdx.x * 256 + threadIdx.x;       // 43,200,000 total (exact)
    int e = gid / 27;
    int p = gid - e * 27;
    int s = src[e], d = dst[e];
    float w = ew[e];
    const float2 v = *(const float2*)(hw + (size_t)s * 54 + p * 2);
    float* o = agg + (size_t)d * 54 + p * 2;
    atomicAdd(o + 0, v.x * w);
    atomicAdd(o + 1, v.y * w);
}

// ---------------------------------------------------------------------------
__global__ void bias_relu_96(float* __restrict__ a, const float* __restrict__ b) {
    int idx = blockIdx.x * 256 + threadIdx.x;       // 2,400,000 float4 groups (exact)
    float4* p = (float4*)a + idx;
    int c4 = (idx % 24) * 4;
    float4 v = *p;
    v.x = fmaxf(v.x + b[c4 + 0], 0.f);
    v.y = fmaxf(v.y + b[c4 + 1], 0.f);
    v.z = fmaxf(v.z + b[c4 + 2], 0.f);
    v.w = fmaxf(v.w + b[c4 + 3], 0.f);
    *p = v;
}

__global__ void bias_relu_54(float* __restrict__ a, const float* __restrict__ b) {
    int idx = blockIdx.x * 256 + threadIdx.x;       // 2,700,000 float2 groups
    if (idx >= 2700000) return;
    float2* p = (float2*)a + idx;
    int c2 = (idx % 27) * 2;
    float2 v = *p;
    v.x = fmaxf(v.x + b[c2 + 0], 0.f);
    v.y = fmaxf(v.y + b[c2 + 1], 0.f);
    *p = v;
}

// ---------------------------------------------------------------------------
// Graph pooling: hg[g,150] = sum over nodes of [h2 | h3]
__global__ void pool_kernel(const float* __restrict__ h2, const float* __restrict__ h3,
                            const int* __restrict__ gids, float* __restrict__ hg) {
    int idx = blockIdx.x * 256 + threadIdx.x;
    if (idx >= NNODES * 150) return;
    int n = idx / 150;
    int c = idx - n * 150;
    float v = (c < 96) ? h2[(size_t)n * 96 + c] : h3[(size_t)n * 54 + (c - 96)];
    atomicAdd(&hg[gids[n] * 150 + c], v);
}

// out[g,5] = hg[g,:] @ Wc[o,:] + bc[o]
__global__ __launch_bounds__(320) void final_kernel(
        const float* __restrict__ hg, const float* __restrict__ Wc,
        const float* __restrict__ bc, float* __restrict__ out) {
    int tid = threadIdx.x;   // 0..319
    int g = tid / 5, o = tid - g * 5;
    float s = bc[o];
    for (int c = 0; c < 150; ++c) s += hg[g * 150 + c] * Wc[o * 150 + c];
    out[g * 5 + o] = s;
}

// ---------------------------------------------------------------------------
extern "C" void kernel_launch(void* const* d_in, const int* in_sizes, int n_in,
                              void* d_out, int out_size, void* d_ws, size_t ws_size,
                              hipStream_t stream) {
    const float* node_feats = (const float*)d_in[0];
    const float* edge_w     = (const float*)d_in[1];
    const int*   src        = (const int*)d_in[2];
    const int*   dst        = (const int*)d_in[3];
    const int*   gids       = (const int*)d_in[4];
    const float* conv_w     = (const float*)d_in[5];
    const float* conv_b     = (const float*)d_in[6];
    const float* bn_gamma   = (const float*)d_in[7];
    const float* bn_beta    = (const float*)d_in[8];
    const float* bn_mean    = (const float*)d_in[9];
    const float* bn_var     = (const float*)d_in[10];
    const float* W1         = (const float*)d_in[11];
    const float* b1         = (const float*)d_in[12];
    const float* W2         = (const float*)d_in[13];
    const float* b2         = (const float*)d_in[14];
    const float* Wc         = (const float*)d_in[15];
    const float* bc         = (const float*)d_in[16];

    float* wsf  = (float*)d_ws;
    float* h1   = wsf + WS_H1;     // then reused as agg1/h2
    float* hw1  = wsf + WS_HW1;    // then reused as hw2
    float* agg1 = wsf + WS_H1;
    float* h2   = agg1;
    float* hw2  = wsf + WS_HW1;
    float* agg2 = wsf + WS_AGG2;
    float* h3   = agg2;
    float* hg   = wsf + WS_HG;
    float* Wt   = wsf + WS_WT;
    float* cb   = wsf + WS_CB;
    float* out  = (float*)d_out;

    // 1. fold BN into conv weights
    prep_weights<<<192, 256, 0, stream>>>(conv_w, conv_b, bn_gamma, bn_beta,
                                          bn_mean, bn_var, Wt, cb);
    // 2. conv + BN + ReLU -> h1 [N,128]
    conv_bn_relu<<<6250, 64, 0, stream>>>(node_feats, Wt, cb, h1);
    // 3. hw1 = h1 @ W1  [N,96]
    gemm16<128, 96, 3><<<6250, 64, 0, stream>>>(h1, W1, hw1, NNODES);
    // 4. agg1 = segment_sum(hw1[src]*ew, dst)   (h1 region now dead -> agg1)
    hipMemsetAsync(agg1, 0, (size_t)NNODES * 96 * 4, stream);
    scatter_96<<<150000, 256, 0, stream>>>(hw1, src, dst, edge_w, agg1);
    // 5. h2 = relu(agg1 + b1) in place
    bias_relu_96<<<9375, 256, 0, stream>>>(agg1, b1);
    // 6. hw2 = h2 @ W2  [N,54]  (hw1 region now dead)
    gemm16<96, 54, 2><<<6250, 64, 0, stream>>>(h2, W2, hw2, NNODES);
    // 7. agg2 = segment_sum(hw2[src]*ew, dst)
    hipMemsetAsync(agg2, 0, (size_t)NNODES * 54 * 4, stream);
    scatter_54<<<168750, 256, 0, stream>>>(hw2, src, dst, edge_w, agg2);
    // 8. h3 = relu(agg2 + b2) in place
    bias_relu_54<<<10547, 256, 0, stream>>>(agg2, b2);
    // 9. graph pooling
    hipMemsetAsync(hg, 0, (size_t)NGRAPHS * 150 * 4, stream);
    pool_kernel<<<58594, 256, 0, stream>>>(h2, h3, gids, hg);
    // 10. final linear
    final_kernel<<<1, 320, 0, stream>>>(hg, Wc, bc, out);
}

// Round 2
// 1045.533 us; speedup vs baseline: 3.2224x; 3.2224x over previous
//
#include <hip/hip_runtime.h>
#include <hip/hip_bf16.h>
#include <cstddef>

#define NNODES 100000
#define NEDGES 1600000
#define NGRAPHS 64

// ---- workspace layout (float offsets) ----
// region A: h1 [N,128] (12.8M floats). After gemm1: first 9.6M = agg1/h2,
//           tail 3.2M = sorted_src (1.6M ints) + sorted_w (1.6M floats).
#define WS_H1    0UL
#define WS_SSRC  9600000UL
#define WS_SW    11200000UL
#define WS_HW1   12800000UL   // [N,96]; reused as hw2
#define WS_AGG2  22400000UL   // [N,54] = h3
#define WS_HG    27800000UL   // [64,150]
#define WS_WT    27809600UL   // folded conv weights
#define WS_CB    27858752UL   // folded conv bias
#define WS_OFF   27858880UL   // 100000 ints (CSR offsets)
// total: 27,958,880 floats = 111.8 MB

// ---------------------------------------------------------------------------
__global__ void prep_weights(const float* __restrict__ conv_w, const float* __restrict__ conv_b,
                             const float* __restrict__ gamma, const float* __restrict__ beta,
                             const float* __restrict__ mean, const float* __restrict__ var,
                             float* __restrict__ Wt, float* __restrict__ bias) {
    int idx = blockIdx.x * 256 + threadIdx.x;
    if (idx < 128) {
        float sc = gamma[idx] * rsqrtf(var[idx] + 1e-5f);
        bias[idx] = (conv_b[idx] - mean[idx]) * sc + beta[idx];
    }
    if (idx < 49152) {
        int j = idx & 3;
        int m = (idx >> 2) & 31;
        int i = (idx >> 7) & 127;
        int k = idx >> 14;
        int o = m + 32 * j;
        float sc = gamma[o] * rsqrtf(var[o] + 1e-5f);
        Wt[idx] = conv_w[o * 384 + i * 3 + k] * sc;
    }
}

// ---------------------------------------------------------------------------
// conv1d(k=3, pad=1) + folded BN + ReLU.  1 wave / block, 16 nodes / block.
__global__ __launch_bounds__(64) void conv_bn_relu(
        const float* __restrict__ x, const float* __restrict__ Wt,
        const float* __restrict__ bias, float* __restrict__ h1) {
    __shared__ float xsT[128][20];
    const int lane = threadIdx.x;
    const int n0 = blockIdx.x * 16;

    for (int r = 0; r < 20; ++r) {
        int n = n0 - 1 + r;
        float v0 = 0.f, v1 = 0.f;
        if (n >= 0 && n < NNODES) {
            v0 = x[(size_t)n * 128 + lane];
            v1 = x[(size_t)n * 128 + lane + 64];
        }
        xsT[lane][r] = v0;
        xsT[lane + 64][r] = v1;
    }
    __syncthreads();

    const int h = lane >> 5;
    const int m = lane & 31;
    float acc[4][8];
#pragma unroll
    for (int j = 0; j < 4; ++j)
#pragma unroll
        for (int t = 0; t < 8; ++t) acc[j][t] = 0.f;

    for (int i = 0; i < 128; ++i) {
        const float4 q0 = *(const float4*)&xsT[i][h * 8 + 0];
        const float4 q1 = *(const float4*)&xsT[i][h * 8 + 4];
        const float4 q2 = *(const float4*)&xsT[i][h * 8 + 8];
        float xv[12] = {q0.x, q0.y, q0.z, q0.w, q1.x, q1.y, q1.z, q1.w,
                        q2.x, q2.y, q2.z, q2.w};
#pragma unroll
        for (int k = 0; k < 3; ++k) {
            const float4 wv = *(const float4*)&Wt[(size_t)(k * 128 + i) * 128 + m * 4];
#pragma unroll
            for (int t = 0; t < 8; ++t) {
                float xa = xv[t + k];
                acc[0][t] += xa * wv.x;
                acc[1][t] += xa * wv.y;
                acc[2][t] += xa * wv.z;
                acc[3][t] += xa * wv.w;
            }
        }
    }

    float b0 = bias[m], b1v = bias[m + 32], b2v = bias[m + 64], b3v = bias[m + 96];
#pragma unroll
    for (int t = 0; t < 8; ++t) {
        int n = n0 + h * 8 + t;
        if (n < NNODES) {
            h1[(size_t)n * 128 + m]      = fmaxf(acc[0][t] + b0, 0.f);
            h1[(size_t)n * 128 + m + 32] = fmaxf(acc[1][t] + b1v, 0.f);
            h1[(size_t)n * 128 + m + 64] = fmaxf(acc[2][t] + b2v, 0.f);
            h1[(size_t)n * 128 + m + 96] = fmaxf(acc[3][t] + b3v, 0.f);
        }
    }
}

// ---------------------------------------------------------------------------
template <int K, int NOUT, int J>
__global__ __launch_bounds__(64) void gemm16(
        const float* __restrict__ A, const float* __restrict__ B,
        float* __restrict__ C, int M) {
    __shared__ float xsT[K][20];
    const int lane = threadIdx.x;
    const int n0 = blockIdx.x * 16;

    for (int r = 0; r < 16; ++r) {
        int n = n0 + r;
#pragma unroll
        for (int cc = 0; cc < K; cc += 64) {
            int c = cc + lane;
            if (c < K) xsT[c][r] = (n < M) ? A[(size_t)n * K + c] : 0.f;
        }
    }
    __syncthreads();

    const int h = lane >> 5;
    const int m = lane & 31;
    float acc[J][8];
#pragma unroll
    for (int j = 0; j < J; ++j)
#pragma unroll
        for (int t = 0; t < 8; ++t) acc[j][t] = 0.f;

    for (int i = 0; i < K; ++i) {
        const float4 q0 = *(const float4*)&xsT[i][h * 8 + 0];
        const float4 q1 = *(const float4*)&xsT[i][h * 8 + 4];
        float xv[8] = {q0.x, q0.y, q0.z, q0.w, q1.x, q1.y, q1.z, q1.w};
#pragma unroll
        for (int j = 0; j < J; ++j) {
            int c = m + 32 * j;
            float w = (c < NOUT) ? B[i * NOUT + c] : 0.f;
#pragma unroll
            for (int t = 0; t < 8; ++t) acc[j][t] += xv[t] * w;
        }
    }

#pragma unroll
    for (int j = 0; j < J; ++j) {
        int c = m + 32 * j;
        if (c < NOUT) {
#pragma unroll
            for (int t = 0; t < 8; ++t) {
                int n = n0 + h * 8 + t;
                if (n < M) C[(size_t)n * NOUT + c] = acc[j][t];
            }
        }
    }
}

// ---------------------------------------------------------------------------
// CSR-by-dst build. 1) histogram  2) one-block scan  3) fill sorted arrays.
__global__ void edge_count(const int* __restrict__ dst, int* __restrict__ off) {
    int e = blockIdx.x * 256 + threadIdx.x;
    if (e < NEDGES) atomicAdd(&off[dst[e]], 1);
}

__global__ __launch_bounds__(1024) void scan_kernel(int* __restrict__ off) {
    __shared__ int part[1024];
    const int t = threadIdx.x;
    const int CH = 98;                 // 1024*98 = 100352 >= NNODES
    const int b0 = t * CH;
    int s = 0;
    for (int i = 0; i < CH; ++i) {
        int idx = b0 + i;
        if (idx < NNODES) s += off[idx];
    }
    part[t] = s;
    __syncthreads();
    for (int d = 1; d < 1024; d <<= 1) {
        int add = (t >= d) ? part[t - d] : 0;
        __syncthreads();
        part[t] += add;
        __syncthreads();
    }
    int base = (t == 0) ? 0 : part[t - 1];
    for (int i = 0; i < CH; ++i) {
        int idx = b0 + i;
        if (idx >= NNODES) break;
        int c = off[idx];
        off[idx] = base;               // exclusive offset
        base += c;
    }
}

// After fill, off[n] holds the END offset of node n (start = off[n-1], or 0).
__global__ void edge_fill(const int* __restrict__ src, const int* __restrict__ dst,
                          const float* __restrict__ ew, int* __restrict__ off,
                          int* __restrict__ ssrc, float* __restrict__ sw) {
    int e = blockIdx.x * 256 + threadIdx.x;
    if (e >= NEDGES) return;
    int d = dst[e];
    int pos = atomicAdd(&off[d], 1);
    ssrc[pos] = src[e];
    sw[pos] = ew[e];
}

// ---------------------------------------------------------------------------
// Gather-aggregate + bias + ReLU, 96 channels: thread = (node, float4 chunk).
__global__ __launch_bounds__(256) void gather_96(
        const int* __restrict__ off, const int* __restrict__ ssrc,
        const float* __restrict__ sw, const float* __restrict__ hw,
        const float* __restrict__ bias, float* __restrict__ out) {
    int gid = blockIdx.x * 256 + threadIdx.x;      // 2,400,000 exact
    int n = gid / 24;
    int p = gid - n * 24;
    int start = (n == 0) ? 0 : off[n - 1];
    int end = off[n];
    float ax = 0.f, ay = 0.f, az = 0.f, aw = 0.f;
    for (int e = start; e < end; ++e) {
        int s = ssrc[e];
        float w = sw[e];
        const float4 v = *(const float4*)(hw + (size_t)s * 96 + p * 4);
        ax += v.x * w; ay += v.y * w; az += v.z * w; aw += v.w * w;
    }
    const float4 b = *(const float4*)(bias + p * 4);
    float4 r;
    r.x = fmaxf(ax + b.x, 0.f);
    r.y = fmaxf(ay + b.y, 0.f);
    r.z = fmaxf(az + b.z, 0.f);
    r.w = fmaxf(aw + b.w, 0.f);
    *(float4*)(out + (size_t)n * 96 + p * 4) = r;
}

// 54 channels: thread = (node, float2 chunk), 27 chunks/node.
__global__ __launch_bounds__(256) void gather_54(
        const int* __restrict__ off, const int* __restrict__ ssrc,
        const float* __restrict__ sw, const float* __restrict__ hw,
        const float* __restrict__ bias, float* __restrict__ out) {
    int gid = blockIdx.x * 256 + threadIdx.x;
    if (gid >= NNODES * 27) return;
    int n = gid / 27;
    int p = gid - n * 27;
    int start = (n == 0) ? 0 : off[n - 1];
    int end = off[n];
    float ax = 0.f, ay = 0.f;
    for (int e = start; e < end; ++e) {
        int s = ssrc[e];
        float w = sw[e];
        const float2 v = *(const float2*)(hw + (size_t)s * 54 + p * 2);
        ax += v.x * w; ay += v.y * w;
    }
    float2 r;
    r.x = fmaxf(ax + bias[p * 2 + 0], 0.f);
    r.y = fmaxf(ay + bias[p * 2 + 1], 0.f);
    *(float2*)(out + (size_t)n * 54 + p * 2) = r;
}

// ---------------------------------------------------------------------------
// Pooling: graph_ids sorted. Block = node range, thread = channel; flush an
// atomic only at graph boundaries.
__global__ __launch_bounds__(192) void pool_kernel(
        const float* __restrict__ h2, const float* __restrict__ h3,
        const int* __restrict__ gids, float* __restrict__ hg) {
    const int c = threadIdx.x;
    const int chunk = (NNODES + gridDim.x - 1) / gridDim.x;
    const int n0 = blockIdx.x * chunk;
    const int n1 = min(n0 + chunk, NNODES);
    if (c >= 150 || n0 >= NNODES) return;
    float acc = 0.f;
    int g = gids[n0];
    for (int n = n0; n < n1; ++n) {
        int gn = gids[n];
        if (gn != g) {
            atomicAdd(&hg[g * 150 + c], acc);
            acc = 0.f;
            g = gn;
        }
        acc += (c < 96) ? h2[(size_t)n * 96 + c] : h3[(size_t)n * 54 + (c - 96)];
    }
    atomicAdd(&hg[g * 150 + c], acc);
}

__global__ __launch_bounds__(320) void final_kernel(
        const float* __restrict__ hg, const float* __restrict__ Wc,
        const float* __restrict__ bc, float* __restrict__ out) {
    int tid = threadIdx.x;
    int g = tid / 5, o = tid - g * 5;
    float s = bc[o];
    for (int c = 0; c < 150; ++c) s += hg[g * 150 + c] * Wc[o * 150 + c];
    out[g * 5 + o] = s;
}

// ---------------------------------------------------------------------------
extern "C" void kernel_launch(void* const* d_in, const int* in_sizes, int n_in,
                              void* d_out, int out_size, void* d_ws, size_t ws_size,
                              hipStream_t stream) {
    const float* node_feats = (const float*)d_in[0];
    const float* edge_w     = (const float*)d_in[1];
    const int*   src        = (const int*)d_in[2];
    const int*   dst        = (const int*)d_in[3];
    const int*   gids       = (const int*)d_in[4];
    const float* conv_w     = (const float*)d_in[5];
    const float* conv_b     = (const float*)d_in[6];
    const float* bn_gamma   = (const float*)d_in[7];
    const float* bn_beta    = (const float*)d_in[8];
    const float* bn_mean    = (const float*)d_in[9];
    const float* bn_var     = (const float*)d_in[10];
    const float* W1         = (const float*)d_in[11];
    const float* b1         = (const float*)d_in[12];
    const float* W2         = (const float*)d_in[13];
    const float* b2         = (const float*)d_in[14];
    const float* Wc         = (const float*)d_in[15];
    const float* bc         = (const float*)d_in[16];

    float* wsf  = (float*)d_ws;
    float* h1   = wsf + WS_H1;
    float* h2   = wsf + WS_H1;              // reuse after gemm1
    int*   ssrc = (int*)(wsf + WS_SSRC);    // h1 tail, valid after gemm1
    float* sw   = wsf + WS_SW;
    float* hw1  = wsf + WS_HW1;
    float* hw2  = wsf + WS_HW1;
    float* h3   = wsf + WS_AGG2;
    float* hg   = wsf + WS_HG;
    float* Wt   = wsf + WS_WT;
    float* cb   = wsf + WS_CB;
    int*   off  = (int*)(wsf + WS_OFF);
    float* out  = (float*)d_out;

    // 1. fold BN into conv weights
    prep_weights<<<192, 256, 0, stream>>>(conv_w, conv_b, bn_gamma, bn_beta,
                                          bn_mean, bn_var, Wt, cb);
    // 2. conv + BN + ReLU -> h1 [N,128]
    conv_bn_relu<<<6250, 64, 0, stream>>>(node_feats, Wt, cb, h1);
    // 3. hw1 = h1 @ W1  [N,96]
    gemm16<128, 96, 3><<<6250, 64, 0, stream>>>(h1, W1, hw1, NNODES);
    // 4. build CSR by dst (h1 now dead; tail holds sorted arrays)
    hipMemsetAsync(off, 0, NNODES * sizeof(int), stream);
    edge_count<<<6250, 256, 0, stream>>>(dst, off);
    scan_kernel<<<1, 1024, 0, stream>>>(off);
    edge_fill<<<6250, 256, 0, stream>>>(src, dst, edge_w, off, ssrc, sw);
    // 5. h2 = relu(gather(hw1) + b1)  [N,96]
    gather_96<<<9375, 256, 0, stream>>>(off, ssrc, sw, hw1, b1, h2);
    // 6. hw2 = h2 @ W2  [N,54]
    gemm16<96, 54, 2><<<6250, 64, 0, stream>>>(h2, W2, hw2, NNODES);
    // 7. h3 = relu(gather(hw2) + b2)  [N,54]
    gather_54<<<10547, 256, 0, stream>>>(off, ssrc, sw, hw2, b2, h3);
    // 8. pooling
    hipMemsetAsync(hg, 0, (size_t)NGRAPHS * 150 * sizeof(float), stream);
    pool_kernel<<<256, 192, 0, stream>>>(h2, h3, gids, hg);
    // 9. final linear
    final_kernel<<<1, 320, 0, stream>>>(hg, Wc, bc, out);
}

// Round 4
// 863.557 us; speedup vs baseline: 3.9015x; 1.2107x over previous
//
#include <hip/hip_runtime.h>
#include <hip/hip_bf16.h>
#include <cstddef>

#define NNODES 100000
#define NEDGES 1600000
#define NGRAPHS 64

// ---- workspace layout (float offsets) ----
// region A: h1 [N,128] (12.8M floats). After gemm1: first 9.6M = agg1/h2,
//           tail 3.2M = sorted_src (1.6M ints) + sorted_w (1.6M floats).
#define WS_H1    0UL
#define WS_SSRC  9600000UL
#define WS_SW    11200000UL
#define WS_HW1   12800000UL   // [N,96]; reused as hw2
#define WS_AGG2  22400000UL   // [N,54] = h3
#define WS_HG    27800000UL   // [64,150]
#define WS_WT    27809600UL   // folded conv weights
#define WS_CB    27858752UL   // folded conv bias
#define WS_OFF   27858880UL   // 100000 ints (CSR offsets)
#define WS_BSUM  27958880UL   // 392 ints (scan block sums)
// total: ~27,959,272 floats = 111.8 MB

// ---------------------------------------------------------------------------
__global__ void prep_weights(const float* __restrict__ conv_w, const float* __restrict__ conv_b,
                             const float* __restrict__ gamma, const float* __restrict__ beta,
                             const float* __restrict__ mean, const float* __restrict__ var,
                             float* __restrict__ Wt, float* __restrict__ bias) {
    int idx = blockIdx.x * 256 + threadIdx.x;
    if (idx < 128) {
        float sc = gamma[idx] * rsqrtf(var[idx] + 1e-5f);
        bias[idx] = (conv_b[idx] - mean[idx]) * sc + beta[idx];
    }
    if (idx < 49152) {
        int j = idx & 3;
        int m = (idx >> 2) & 31;
        int i = (idx >> 7) & 127;
        int k = idx >> 14;
        int o = m + 32 * j;
        float sc = gamma[o] * rsqrtf(var[o] + 1e-5f);
        Wt[idx] = conv_w[o * 384 + i * 3 + k] * sc;
    }
}

// ---------------------------------------------------------------------------
// conv1d(k=3, pad=1) + folded BN + ReLU.  1 wave / block, 16 nodes / block.
__global__ __launch_bounds__(64) void conv_bn_relu(
        const float* __restrict__ x, const float* __restrict__ Wt,
        const float* __restrict__ bias, float* __restrict__ h1) {
    __shared__ float xsT[128][20];
    const int lane = threadIdx.x;
    const int n0 = blockIdx.x * 16;

    for (int r = 0; r < 20; ++r) {
        int n = n0 - 1 + r;
        float v0 = 0.f, v1 = 0.f;
        if (n >= 0 && n < NNODES) {
            v0 = x[(size_t)n * 128 + lane];
            v1 = x[(size_t)n * 128 + lane + 64];
        }
        xsT[lane][r] = v0;
        xsT[lane + 64][r] = v1;
    }
    __syncthreads();

    const int h = lane >> 5;
    const int m = lane & 31;
    float acc[4][8];
#pragma unroll
    for (int j = 0; j < 4; ++j)
#pragma unroll
        for (int t = 0; t < 8; ++t) acc[j][t] = 0.f;

    for (int i = 0; i < 128; ++i) {
        const float4 q0 = *(const float4*)&xsT[i][h * 8 + 0];
        const float4 q1 = *(const float4*)&xsT[i][h * 8 + 4];
        const float4 q2 = *(const float4*)&xsT[i][h * 8 + 8];
        float xv[12] = {q0.x, q0.y, q0.z, q0.w, q1.x, q1.y, q1.z, q1.w,
                        q2.x, q2.y, q2.z, q2.w};
#pragma unroll
        for (int k = 0; k < 3; ++k) {
            const float4 wv = *(const float4*)&Wt[(size_t)(k * 128 + i) * 128 + m * 4];
#pragma unroll
            for (int t = 0; t < 8; ++t) {
                float xa = xv[t + k];
                acc[0][t] += xa * wv.x;
                acc[1][t] += xa * wv.y;
                acc[2][t] += xa * wv.z;
                acc[3][t] += xa * wv.w;
            }
        }
    }

    float b0 = bias[m], b1v = bias[m + 32], b2v = bias[m + 64], b3v = bias[m + 96];
#pragma unroll
    for (int t = 0; t < 8; ++t) {
        int n = n0 + h * 8 + t;
        if (n < NNODES) {
            h1[(size_t)n * 128 + m]      = fmaxf(acc[0][t] + b0, 0.f);
            h1[(size_t)n * 128 + m + 32] = fmaxf(acc[1][t] + b1v, 0.f);
            h1[(size_t)n * 128 + m + 64] = fmaxf(acc[2][t] + b2v, 0.f);
            h1[(size_t)n * 128 + m + 96] = fmaxf(acc[3][t] + b3v, 0.f);
        }
    }
}

// ---------------------------------------------------------------------------
template <int K, int NOUT, int J>
__global__ __launch_bounds__(64) void gemm16(
        const float* __restrict__ A, const float* __restrict__ B,
        float* __restrict__ C, int M) {
    __shared__ float xsT[K][20];
    const int lane = threadIdx.x;
    const int n0 = blockIdx.x * 16;

    for (int r = 0; r < 16; ++r) {
        int n = n0 + r;
#pragma unroll
        for (int cc = 0; cc < K; cc += 64) {
            int c = cc + lane;
            if (c < K) xsT[c][r] = (n < M) ? A[(size_t)n * K + c] : 0.f;
        }
    }
    __syncthreads();

    const int h = lane >> 5;
    const int m = lane & 31;
    float acc[J][8];
#pragma unroll
    for (int j = 0; j < J; ++j)
#pragma unroll
        for (int t = 0; t < 8; ++t) acc[j][t] = 0.f;

    for (int i = 0; i < K; ++i) {
        const float4 q0 = *(const float4*)&xsT[i][h * 8 + 0];
        const float4 q1 = *(const float4*)&xsT[i][h * 8 + 4];
        float xv[8] = {q0.x, q0.y, q0.z, q0.w, q1.x, q1.y, q1.z, q1.w};
#pragma unroll
        for (int j = 0; j < J; ++j) {
            int c = m + 32 * j;
            float w = (c < NOUT) ? B[i * NOUT + c] : 0.f;
#pragma unroll
            for (int t = 0; t < 8; ++t) acc[j][t] += xv[t] * w;
        }
    }

#pragma unroll
    for (int j = 0; j < J; ++j) {
        int c = m + 32 * j;
        if (c < NOUT) {
#pragma unroll
            for (int t = 0; t < 8; ++t) {
                int n = n0 + h * 8 + t;
                if (n < M) C[(size_t)n * NOUT + c] = acc[j][t];
            }
        }
    }
}

// ---------------------------------------------------------------------------
// CSR-by-dst build: histogram -> 3-phase hierarchical exclusive scan -> fill.
__global__ void edge_count(const int* __restrict__ dst, int* __restrict__ off) {
    int e = blockIdx.x * 256 + threadIdx.x;
    if (e < NEDGES) atomicAdd(&off[dst[e]], 1);
}

// Phase 1: per-block exclusive scan (in place) + block sums.  392 blocks.
__global__ __launch_bounds__(256) void scan_block(int* __restrict__ off, int* __restrict__ bsum) {
    __shared__ int s[256];
    const int t = threadIdx.x;
    const int idx = blockIdx.x * 256 + t;
    int v = (idx < NNODES) ? off[idx] : 0;
    s[t] = v;
    __syncthreads();
    for (int d = 1; d < 256; d <<= 1) {
        int add = (t >= d) ? s[t - d] : 0;
        __syncthreads();
        s[t] += add;
        __syncthreads();
    }
    if (idx < NNODES) off[idx] = s[t] - v;   // exclusive within block
    if (t == 255) bsum[blockIdx.x] = s[255];
}

// Phase 2: exclusive scan of 392 block sums.  One 512-thread block.
__global__ __launch_bounds__(512) void scan_bsum(int* __restrict__ bsum) {
    __shared__ int s[512];
    const int t = threadIdx.x;
    int v = (t < 392) ? bsum[t] : 0;
    s[t] = v;
    __syncthreads();
    for (int d = 1; d < 512; d <<= 1) {
        int add = (t >= d) ? s[t - d] : 0;
        __syncthreads();
        s[t] += add;
        __syncthreads();
    }
    if (t < 392) bsum[t] = s[t] - v;         // exclusive block base
}

// Phase 3: add block base.
__global__ __launch_bounds__(256) void scan_add(int* __restrict__ off, const int* __restrict__ bsum) {
    int idx = blockIdx.x * 256 + threadIdx.x;
    if (idx < NNODES) off[idx] += bsum[blockIdx.x];
}

// After fill, off[n] holds the END offset of node n (start = off[n-1], or 0).
__global__ void edge_fill(const int* __restrict__ src, const int* __restrict__ dst,
                          const float* __restrict__ ew, int* __restrict__ off,
                          int* __restrict__ ssrc, float* __restrict__ sw) {
    int e = blockIdx.x * 256 + threadIdx.x;
    if (e >= NEDGES) return;
    int d = dst[e];
    int pos = atomicAdd(&off[d], 1);
    ssrc[pos] = src[e];
    sw[pos] = ew[e];
}

// ---------------------------------------------------------------------------
// Gather-aggregate + bias + ReLU, 96 channels: thread = (node, float4 chunk).
__global__ __launch_bounds__(256) void gather_96(
        const int* __restrict__ off, const int* __restrict__ ssrc,
        const float* __restrict__ sw, const float* __restrict__ hw,
        const float* __restrict__ bias, float* __restrict__ out) {
    int gid = blockIdx.x * 256 + threadIdx.x;      // 2,400,000 exact
    int n = gid / 24;
    int p = gid - n * 24;
    int start = (n == 0) ? 0 : off[n - 1];
    int end = off[n];
    float ax = 0.f, ay = 0.f, az = 0.f, aw = 0.f;
    for (int e = start; e < end; ++e) {
        int s = ssrc[e];
        float w = sw[e];
        const float4 v = *(const float4*)(hw + (size_t)s * 96 + p * 4);
        ax += v.x * w; ay += v.y * w; az += v.z * w; aw += v.w * w;
    }
    const float4 b = *(const float4*)(bias + p * 4);
    float4 r;
    r.x = fmaxf(ax + b.x, 0.f);
    r.y = fmaxf(ay + b.y, 0.f);
    r.z = fmaxf(az + b.z, 0.f);
    r.w = fmaxf(aw + b.w, 0.f);
    *(float4*)(out + (size_t)n * 96 + p * 4) = r;
}

// 54 channels: thread = (node, float2 chunk), 27 chunks/node.
__global__ __launch_bounds__(256) void gather_54(
        const int* __restrict__ off, const int* __restrict__ ssrc,
        const float* __restrict__ sw, const float* __restrict__ hw,
        const float* __restrict__ bias, float* __restrict__ out) {
    int gid = blockIdx.x * 256 + threadIdx.x;
    if (gid >= NNODES * 27) return;
    int n = gid / 27;
    int p = gid - n * 27;
    int start = (n == 0) ? 0 : off[n - 1];
    int end = off[n];
    float ax = 0.f, ay = 0.f;
    for (int e = start; e < end; ++e) {
        int s = ssrc[e];
        float w = sw[e];
        const float2 v = *(const float2*)(hw + (size_t)s * 54 + p * 2);
        ax += v.x * w; ay += v.y * w;
    }
    float2 r;
    r.x = fmaxf(ax + bias[p * 2 + 0], 0.f);
    r.y = fmaxf(ay + bias[p * 2 + 1], 0.f);
    *(float2*)(out + (size_t)n * 54 + p * 2) = r;
}

// ---------------------------------------------------------------------------
// Pooling: graph_ids sorted. Block = node range, thread = channel; flush an
// atomic only at graph boundaries.
__global__ __launch_bounds__(192) void pool_kernel(
        const float* __restrict__ h2, const float* __restrict__ h3,
        const int* __restrict__ gids, float* __restrict__ hg) {
    const int c = threadIdx.x;
    const int chunk = (NNODES + gridDim.x - 1) / gridDim.x;
    const int n0 = blockIdx.x * chunk;
    const int n1 = min(n0 + chunk, NNODES);
    if (c >= 150 || n0 >= NNODES) return;
    float acc = 0.f;
    int g = gids[n0];
    for (int n = n0; n < n1; ++n) {
        int gn = gids[n];
        if (gn != g) {
            atomicAdd(&hg[g * 150 + c], acc);
            acc = 0.f;
            g = gn;
        }
        acc += (c < 96) ? h2[(size_t)n * 96 + c] : h3[(size_t)n * 54 + (c - 96)];
    }
    atomicAdd(&hg[g * 150 + c], acc);
}

__global__ __launch_bounds__(320) void final_kernel(
        const float* __restrict__ hg, const float* __restrict__ Wc,
        const float* __restrict__ bc, float* __restrict__ out) {
    int tid = threadIdx.x;
    int g = tid / 5, o = tid - g * 5;
    float s = bc[o];
    for (int c = 0; c < 150; ++c) s += hg[g * 150 + c] * Wc[o * 150 + c];
    out[g * 5 + o] = s;
}

// ---------------------------------------------------------------------------
extern "C" void kernel_launch(void* const* d_in, const int* in_sizes, int n_in,
                              void* d_out, int out_size, void* d_ws, size_t ws_size,
                              hipStream_t stream) {
    const float* node_feats = (const float*)d_in[0];
    const float* edge_w     = (const float*)d_in[1];
    const int*   src        = (const int*)d_in[2];
    const int*   dst        = (const int*)d_in[3];
    const int*   gids       = (const int*)d_in[4];
    const float* conv_w     = (const float*)d_in[5];
    const float* conv_b     = (const float*)d_in[6];
    const float* bn_gamma   = (const float*)d_in[7];
    const float* bn_beta    = (const float*)d_in[8];
    const float* bn_mean    = (const float*)d_in[9];
    const float* bn_var     = (const float*)d_in[10];
    const float* W1         = (const float*)d_in[11];
    const float* b1         = (const float*)d_in[12];
    const float* W2         = (const float*)d_in[13];
    const float* b2         = (const float*)d_in[14];
    const float* Wc         = (const float*)d_in[15];
    const float* bc         = (const float*)d_in[16];

    float* wsf  = (float*)d_ws;
    float* h1   = wsf + WS_H1;
    float* h2   = wsf + WS_H1;              // reuse after gemm1
    int*   ssrc = (int*)(wsf + WS_SSRC);    // h1 tail, valid after gemm1
    float* sw   = wsf + WS_SW;
    float* hw1  = wsf + WS_HW1;
    float* hw2  = wsf + WS_HW1;
    float* h3   = wsf + WS_AGG2;
    float* hg   = wsf + WS_HG;
    float* Wt   = wsf + WS_WT;
    float* cb   = wsf + WS_CB;
    int*   off  = (int*)(wsf + WS_OFF);
    int*   bsum = (int*)(wsf + WS_BSUM);
    float* out  = (float*)d_out;

    // 1. fold BN into conv weights
    prep_weights<<<192, 256, 0, stream>>>(conv_w, conv_b, bn_gamma, bn_beta,
                                          bn_mean, bn_var, Wt, cb);
    // 2. conv + BN + ReLU -> h1 [N,128]
    conv_bn_relu<<<6250, 64, 0, stream>>>(node_feats, Wt, cb, h1);
    // 3. hw1 = h1 @ W1  [N,96]
    gemm16<128, 96, 3><<<6250, 64, 0, stream>>>(h1, W1, hw1, NNODES);
    // 4. build CSR by dst (h1 now dead; tail holds sorted arrays)
    hipMemsetAsync(off, 0, NNODES * sizeof(int), stream);
    edge_count<<<6250, 256, 0, stream>>>(dst, off);
    scan_block<<<392, 256, 0, stream>>>(off, bsum);
    scan_bsum<<<1, 512, 0, stream>>>(bsum);
    scan_add<<<392, 256, 0, stream>>>(off, bsum);
    edge_fill<<<6250, 256, 0, stream>>>(src, dst, edge_w, off, ssrc, sw);
    // 5. h2 = relu(gather(hw1) + b1)  [N,96]
    gather_96<<<9375, 256, 0, stream>>>(off, ssrc, sw, hw1, b1, h2);
    // 6. hw2 = h2 @ W2  [N,54]
    gemm16<96, 54, 2><<<6250, 64, 0, stream>>>(h2, W2, hw2, NNODES);
    // 7. h3 = relu(gather(hw2) + b2)  [N,54]
    gather_54<<<10547, 256, 0, stream>>>(off, ssrc, sw, hw2, b2, h3);
    // 8. pooling
    hipMemsetAsync(hg, 0, (size_t)NGRAPHS * 150 * sizeof(float), stream);
    pool_kernel<<<256, 192, 0, stream>>>(h2, h3, gids, hg);
    // 9. final linear
    final_kernel<<<1, 320, 0, stream>>>(hg, Wc, bc, out);
}

// Round 6
// 596.873 us; speedup vs baseline: 5.6447x; 1.4468x over previous
//
#include <hip/hip_runtime.h>
#include <hip/hip_bf16.h>
#include <cstddef>

#define NNODES 100000
#define NEDGES 1600000
#define NGRAPHS 64

typedef unsigned short u16;
typedef __attribute__((ext_vector_type(8))) short bf16x8;   // 8 bf16 = 4 VGPR
typedef __attribute__((ext_vector_type(4))) float f32x4;

__device__ inline float bf2f(u16 u) {
    union { unsigned int i; float f; } x; x.i = ((unsigned int)u) << 16; return x.f;
}
__device__ inline u16 f2bf(float f) {   // round-to-nearest-even
    union { float f; unsigned int i; } x; x.f = f;
    unsigned int r = x.i + 0x7FFFu + ((x.i >> 16) & 1u);
    return (u16)(r >> 16);
}

// ---- workspace layout (BYTE offsets), total ~103.0 MB ----
// h1   [N,128] bf16 @ 0          (25,600,000)
// hw1  [N, 96] bf16 @ 25,600,000 (19,200,000)
// h2   [N, 96] bf16 @ 44,800,000 (19,200,000)
// hw2  [N, 64] bf16 @ 64,000,000 (12,800,000)  (cols 54..63 are zero-pad)
// h3   [N, 64] bf16 @ 76,800,000 (12,800,000)
// ssrc [E] int      @ 89,600,000 ( 6,400,000)
// sw   [E] f32      @ 96,000,000 ( 6,400,000)
// off  [N] int      @102,400,000 (   400,000)
// bsum [392] int    @102,800,000 (     1,600)
// BpC  conv Bpack   @102,801,600 (    98,304)   [12][8][64][8] bf16
// Bp1  W1 Bpack     @102,899,904 (    24,576)   [4][6][64][8]
// Bp2  W2 Bpack     @102,924,480 (    12,288)   [3][4][64][8]
// cb   f32[128]     @102,936,768 (       512)
// hg   f32[64*150]  @102,937,280 (    38,400)

// ---------------------------------------------------------------------------
// Fold BN into conv weights + pack all weight matrices into MFMA fragment
// order: Bpack[ks][ct][lane][j] = B[k = ks*32 + (lane>>4)*8 + j][c = ct*16 + (lane&15)]
__global__ __launch_bounds__(256) void prep_pack(
        const float* __restrict__ conv_w, const float* __restrict__ conv_b,
        const float* __restrict__ gamma, const float* __restrict__ beta,
        const float* __restrict__ mean, const float* __restrict__ var,
        const float* __restrict__ W1, const float* __restrict__ W2,
        u16* __restrict__ BpC, u16* __restrict__ Bp1, u16* __restrict__ Bp2,
        float* __restrict__ cb) {
    int idx = blockIdx.x * 256 + threadIdx.x;   // 264*256 = 67,584 exact
    if (idx < 128) {
        float sc = gamma[idx] * rsqrtf(var[idx] + 1e-5f);
        cb[idx] = (conv_b[idx] - mean[idx]) * sc + beta[idx];
    }
    if (idx < 49152) {                      // conv: B[kk][o], kk = k*128+i
        int j = idx & 7, l = (idx >> 3) & 63;
        int ct = (idx >> 9) & 7, ks = idx >> 12;        // ks<12
        int kk = ks * 32 + (l >> 4) * 8 + j;
        int o  = ct * 16 + (l & 15);
        int k = kk >> 7, i = kk & 127;
        float sc = gamma[o] * rsqrtf(var[o] + 1e-5f);
        BpC[idx] = f2bf(conv_w[o * 384 + i * 3 + k] * sc);
    }
    int i1 = idx - 49152;
    if (i1 >= 0 && i1 < 12288) {            // W1 [128][96]
        int j = i1 & 7, l = (i1 >> 3) & 63;
        int rest = i1 >> 9; int ct = rest % 6, ks = rest / 6;   // ks<4
        int k = ks * 32 + (l >> 4) * 8 + j;
        int c = ct * 16 + (l & 15);
        Bp1[i1] = f2bf(W1[k * 96 + c]);
    }
    int i2 = idx - 61440;
    if (i2 >= 0 && i2 < 6144) {             // W2 [96][54] padded to 64 cols
        int j = i2 & 7, l = (i2 >> 3) & 63;
        int rest = i2 >> 9; int ct = rest & 3, ks = rest >> 2;  // ks<3
        int k = ks * 32 + (l >> 4) * 8 + j;
        int c = ct * 16 + (l & 15);
        Bp2[i2] = f2bf(c < 54 ? W2[k * 54 + c] : 0.f);
    }
}

// ---------------------------------------------------------------------------
// conv1d(k=3,pad=1)+BN+ReLU as MFMA GEMM, K=384 (kk=k*128+i).
// Block: 256 thr = 4 waves, 64 nodes; wave w: rows [n0+16w, +16) x 128 cols.
__global__ __launch_bounds__(256) void conv_mfma(
        const float* __restrict__ x, const u16* __restrict__ Bp,
        const float* __restrict__ bias, u16* __restrict__ h1) {
    __shared__ u16 xs[66][136];             // rows n0-1 .. n0+64, pitch-padded
    const int tid = threadIdx.x;
    const int n0 = blockIdx.x * 64;

    {   // stage 66 rows x 128 ch fp32 -> bf16
        int c4 = (tid & 31) * 4;
        int rr = tid >> 5;                  // 0..7
        for (int pass = 0; pass < 9; ++pass) {
            int r = rr + pass * 8;
            if (r < 66) {
                int n = n0 - 1 + r;
                float4 v = make_float4(0.f, 0.f, 0.f, 0.f);
                if (n >= 0 && n < NNODES) v = *(const float4*)&x[(size_t)n * 128 + c4];
                xs[r][c4 + 0] = f2bf(v.x);
                xs[r][c4 + 1] = f2bf(v.y);
                xs[r][c4 + 2] = f2bf(v.z);
                xs[r][c4 + 3] = f2bf(v.w);
            }
        }
    }
    __syncthreads();

    const int lane = tid & 63, w = tid >> 6;
    const int l15 = lane & 15, g = lane >> 4;
    f32x4 acc[8];
#pragma unroll
    for (int ct = 0; ct < 8; ++ct) acc[ct] = f32x4{0.f, 0.f, 0.f, 0.f};

    for (int ks = 0; ks < 12; ++ks) {
        int k = ks >> 2;                                // conv tap
        int icol = (ks & 3) * 32 + g * 8;               // in-channel base
        bf16x8 a = *(const bf16x8*)&xs[w * 16 + l15 + k][icol];
        const u16* bp = Bp + (((size_t)ks * 8) * 64 + lane) * 8;
#pragma unroll
        for (int ct = 0; ct < 8; ++ct) {
            bf16x8 b = *(const bf16x8*)(bp + (size_t)ct * 512);
            acc[ct] = __builtin_amdgcn_mfma_f32_16x16x32_bf16(a, b, acc[ct], 0, 0, 0);
        }
    }

#pragma unroll
    for (int ct = 0; ct < 8; ++ct) {
        int c = ct * 16 + l15;
        float bv = bias[c];
#pragma unroll
        for (int q = 0; q < 4; ++q) {
            int n = n0 + w * 16 + g * 4 + q;
            if (n < NNODES)
                h1[(size_t)n * 128 + c] = f2bf(fmaxf(acc[ct][q] + bv, 0.f));
        }
    }
}

// ---------------------------------------------------------------------------
// C[M,NOUT](bf16) = A[M,K](bf16) @ Bpack.  Block: 4 waves, 64 rows.
template <int K, int CT, int KS, int NOUT>
__global__ __launch_bounds__(256) void gemm_mfma(
        const u16* __restrict__ A, const u16* __restrict__ Bp, u16* __restrict__ C) {
    __shared__ u16 xs[64][K + 8];
    const int tid = threadIdx.x;
    const int n0 = blockIdx.x * 64;

    for (int ch = tid; ch < 64 * (K / 8); ch += 256) {
        int r = ch / (K / 8);
        int c8 = (ch % (K / 8)) * 8;
        int n = n0 + r;
        bf16x8 v{};
        if (n < NNODES) v = *(const bf16x8*)&A[(size_t)n * K + c8];
        *(bf16x8*)&xs[r][c8] = v;
    }
    __syncthreads();

    const int lane = tid & 63, w = tid >> 6;
    const int l15 = lane & 15, g = lane >> 4;
    f32x4 acc[CT];
#pragma unroll
    for (int ct = 0; ct < CT; ++ct) acc[ct] = f32x4{0.f, 0.f, 0.f, 0.f};

#pragma unroll
    for (int ks = 0; ks < KS; ++ks) {
        bf16x8 a = *(const bf16x8*)&xs[w * 16 + l15][ks * 32 + g * 8];
        const u16* bp = Bp + (((size_t)ks * CT) * 64 + lane) * 8;
#pragma unroll
        for (int ct = 0; ct < CT; ++ct) {
            bf16x8 b = *(const bf16x8*)(bp + (size_t)ct * 512);
            acc[ct] = __builtin_amdgcn_mfma_f32_16x16x32_bf16(a, b, acc[ct], 0, 0, 0);
        }
    }

#pragma unroll
    for (int ct = 0; ct < CT; ++ct) {
        int c = ct * 16 + l15;
#pragma unroll
        for (int q = 0; q < 4; ++q) {
            int n = n0 + w * 16 + g * 4 + q;
            if (n < NNODES) C[(size_t)n * NOUT + c] = f2bf(acc[ct][q]);
        }
    }
}

// ---------------------------------------------------------------------------
// CSR-by-dst build: histogram -> 3-phase hierarchical exclusive scan -> fill.
__global__ void edge_count(const int* __restrict__ dst, int* __restrict__ off) {
    int e = blockIdx.x * 256 + threadIdx.x;
    if (e < NEDGES) atomicAdd(&off[dst[e]], 1);
}

__global__ __launch_bounds__(256) void scan_block(int* __restrict__ off, int* __restrict__ bsum) {
    __shared__ int s[256];
    const int t = threadIdx.x;
    const int idx = blockIdx.x * 256 + t;
    int v = (idx < NNODES) ? off[idx] : 0;
    s[t] = v;
    __syncthreads();
    for (int d = 1; d < 256; d <<= 1) {
        int add = (t >= d) ? s[t - d] : 0;
        __syncthreads();
        s[t] += add;
        __syncthreads();
    }
    if (idx < NNODES) off[idx] = s[t] - v;
    if (t == 255) bsum[blockIdx.x] = s[255];
}

__global__ __launch_bounds__(512) void scan_bsum(int* __restrict__ bsum) {
    __shared__ int s[512];
    const int t = threadIdx.x;
    int v = (t < 392) ? bsum[t] : 0;
    s[t] = v;
    __syncthreads();
    for (int d = 1; d < 512; d <<= 1) {
        int add = (t >= d) ? s[t - d] : 0;
        __syncthreads();
        s[t] += add;
        __syncthreads();
    }
    if (t < 392) bsum[t] = s[t] - v;
}

__global__ __launch_bounds__(256) void scan_add(int* __restrict__ off, const int* __restrict__ bsum) {
    int idx = blockIdx.x * 256 + threadIdx.x;
    if (idx < NNODES) off[idx] += bsum[blockIdx.x];
}

__global__ void edge_fill(const int* __restrict__ src, const int* __restrict__ dst,
                          const float* __restrict__ ew, int* __restrict__ off,
                          int* __restrict__ ssrc, float* __restrict__ sw) {
    int e = blockIdx.x * 256 + threadIdx.x;
    if (e >= NEDGES) return;
    int d = dst[e];
    int pos = atomicAdd(&off[d], 1);
    ssrc[pos] = src[e];
    sw[pos] = ew[e];
}

// ---------------------------------------------------------------------------
// Gather-aggregate + bias + ReLU (bf16 in/out, fp32 accum).
// 96 ch: thread = (node, 16B chunk p<12).
__global__ __launch_bounds__(256) void gather_96(
        const int* __restrict__ off, const int* __restrict__ ssrc,
        const float* __restrict__ sw, const u16* __restrict__ hw,
        const float* __restrict__ bias, u16* __restrict__ out) {
    int gid = blockIdx.x * 256 + threadIdx.x;
    if (gid >= NNODES * 12) return;
    int n = gid / 12, p = gid - n * 12;
    int s0 = n ? off[n - 1] : 0, e1 = off[n];
    float acc[8] = {0.f, 0.f, 0.f, 0.f, 0.f, 0.f, 0.f, 0.f};
    for (int e = s0; e < e1; ++e) {
        int s = ssrc[e];
        float w = sw[e];
        bf16x8 v = *(const bf16x8*)&hw[(size_t)s * 96 + p * 8];
#pragma unroll
        for (int j = 0; j < 8; ++j) acc[j] += w * bf2f((u16)v[j]);
    }
    u16 r[8];
#pragma unroll
    for (int j = 0; j < 8; ++j) r[j] = f2bf(fmaxf(acc[j] + bias[p * 8 + j], 0.f));
    *(bf16x8*)&out[(size_t)n * 96 + p * 8] = *(bf16x8*)r;
}

// 64-wide (54 valid): thread = (node, 16B chunk p<8).
__global__ __launch_bounds__(256) void gather_64(
        const int* __restrict__ off, const int* __restrict__ ssrc,
        const float* __restrict__ sw, const u16* __restrict__ hw,
        const float* __restrict__ bias, u16* __restrict__ out) {
    int gid = blockIdx.x * 256 + threadIdx.x;
    if (gid >= NNODES * 8) return;
    int n = gid / 8, p = gid - n * 8;
    int s0 = n ? off[n - 1] : 0, e1 = off[n];
    float acc[8] = {0.f, 0.f, 0.f, 0.f, 0.f, 0.f, 0.f, 0.f};
    for (int e = s0; e < e1; ++e) {
        int s = ssrc[e];
        float w = sw[e];
        bf16x8 v = *(const bf16x8*)&hw[(size_t)s * 64 + p * 8];
#pragma unroll
        for (int j = 0; j < 8; ++j) acc[j] += w * bf2f((u16)v[j]);
    }
    u16 r[8];
#pragma unroll
    for (int j = 0; j < 8; ++j) {
        int c = p * 8 + j;
        float bv = (c < 54) ? bias[c] : 0.f;
        r[j] = f2bf(fmaxf(acc[j] + bv, 0.f));
    }
    *(bf16x8*)&out[(size_t)n * 64 + p * 8] = *(bf16x8*)r;
}

// ---------------------------------------------------------------------------
// Pooling over sorted graph_ids: block = node range, thread = channel.
__global__ __launch_bounds__(192) void pool_kernel(
        const u16* __restrict__ h2, const u16* __restrict__ h3,
        const int* __restrict__ gids, float* __restrict__ hg) {
    const int c = threadIdx.x;
    const int chunk = (NNODES + gridDim.x - 1) / gridDim.x;
    const int n0 = blockIdx.x * chunk;
    const int n1 = min(n0 + chunk, NNODES);
    if (c >= 150 || n0 >= NNODES) return;
    float acc = 0.f;
    int g = gids[n0];
    for (int n = n0; n < n1; ++n) {
        int gn = gids[n];
        if (gn != g) {
            atomicAdd(&hg[g * 150 + c], acc);
            acc = 0.f;
            g = gn;
        }
        acc += (c < 96) ? bf2f(h2[(size_t)n * 96 + c]) : bf2f(h3[(size_t)n * 64 + (c - 96)]);
    }
    atomicAdd(&hg[g * 150 + c], acc);
}

__global__ __launch_bounds__(320) void final_kernel(
        const float* __restrict__ hg, const float* __restrict__ Wc,
        const float* __restrict__ bc, float* __restrict__ out) {
    int tid = threadIdx.x;
    int g = tid / 5, o = tid - g * 5;
    float s = bc[o];
    for (int c = 0; c < 150; ++c) s += hg[g * 150 + c] * Wc[o * 150 + c];
    out[g * 5 + o] = s;
}

// ---------------------------------------------------------------------------
extern "C" void kernel_launch(void* const* d_in, const int* in_sizes, int n_in,
                              void* d_out, int out_size, void* d_ws, size_t ws_size,
                              hipStream_t stream) {
    const float* node_feats = (const float*)d_in[0];
    const float* edge_w     = (const float*)d_in[1];
    const int*   src        = (const int*)d_in[2];
    const int*   dst        = (const int*)d_in[3];
    const int*   gids       = (const int*)d_in[4];
    const float* conv_w     = (const float*)d_in[5];
    const float* conv_b     = (const float*)d_in[6];
    const float* bn_gamma   = (const float*)d_in[7];
    const float* bn_beta    = (const float*)d_in[8];
    const float* bn_mean    = (const float*)d_in[9];
    const float* bn_var     = (const float*)d_in[10];
    const float* W1         = (const float*)d_in[11];
    const float* b1         = (const float*)d_in[12];
    const float* W2         = (const float*)d_in[13];
    const float* b2         = (const float*)d_in[14];
    const float* Wc         = (const float*)d_in[15];
    const float* bc         = (const float*)d_in[16];

    char* W = (char*)d_ws;
    u16*   h1   = (u16*)(W + 0);
    u16*   hw1  = (u16*)(W + 25600000);
    u16*   h2   = (u16*)(W + 44800000);
    u16*   hw2  = (u16*)(W + 64000000);
    u16*   h3   = (u16*)(W + 76800000);
    int*   ssrc = (int*)(W + 89600000);
    float* sw   = (float*)(W + 96000000);
    int*   off  = (int*)(W + 102400000);
    int*   bsum = (int*)(W + 102800000);
    u16*   BpC  = (u16*)(W + 102801600);
    u16*   Bp1  = (u16*)(W + 102899904);
    u16*   Bp2  = (u16*)(W + 102924480);
    float* cb   = (float*)(W + 102936768);
    float* hg   = (float*)(W + 102937280);
    float* out  = (float*)d_out;

    // 1. fold BN + pack weights into MFMA fragment order
    prep_pack<<<264, 256, 0, stream>>>(conv_w, conv_b, bn_gamma, bn_beta,
                                       bn_mean, bn_var, W1, W2, BpC, Bp1, Bp2, cb);
    // 2. conv+BN+ReLU (MFMA) -> h1 bf16 [N,128]
    conv_mfma<<<1563, 256, 0, stream>>>(node_feats, BpC, cb, h1);
    // 3. hw1 = h1 @ W1 (MFMA) -> bf16 [N,96]
    gemm_mfma<128, 6, 4, 96><<<1563, 256, 0, stream>>>(h1, Bp1, hw1);
    // 4. build CSR by dst
    hipMemsetAsync(off, 0, NNODES * sizeof(int), stream);
    edge_count<<<6250, 256, 0, stream>>>(dst, off);
    scan_block<<<392, 256, 0, stream>>>(off, bsum);
    scan_bsum<<<1, 512, 0, stream>>>(bsum);
    scan_add<<<392, 256, 0, stream>>>(off, bsum);
    edge_fill<<<6250, 256, 0, stream>>>(src, dst, edge_w, off, ssrc, sw);
    // 5. h2 = relu(gather(hw1) + b1)  bf16 [N,96]
    gather_96<<<4688, 256, 0, stream>>>(off, ssrc, sw, hw1, b1, h2);
    // 6. hw2 = h2 @ W2 (MFMA) -> bf16 [N,64] (54 valid, pad zero)
    gemm_mfma<96, 4, 3, 64><<<1563, 256, 0, stream>>>(h2, Bp2, hw2);
    // 7. h3 = relu(gather(hw2) + b2)  bf16 [N,64]
    gather_64<<<3125, 256, 0, stream>>>(off, ssrc, sw, hw2, b2, h3);
    // 8. pooling
    hipMemsetAsync(hg, 0, (size_t)NGRAPHS * 150 * sizeof(float), stream);
    pool_kernel<<<256, 192, 0, stream>>>(h2, h3, gids, hg);
    // 9. final linear
    final_kernel<<<1, 320, 0, stream>>>(hg, Wc, bc, out);
}

// Round 7
// 490.620 us; speedup vs baseline: 6.8672x; 1.2166x over previous
//
#include <hip/hip_runtime.h>
#include <hip/hip_bf16.h>
#include <cstddef>

#define NNODES 100000
#define NEDGES 1600000
#define NGRAPHS 64
#define POOL_BLOCKS 2048

typedef unsigned short u16;
typedef __attribute__((ext_vector_type(8))) short bf16x8;   // 8 bf16 = 4 VGPR
typedef __attribute__((ext_vector_type(4))) float f32x4;

__device__ inline float bf2f(u16 u) {
    union { unsigned int i; float f; } x; x.i = ((unsigned int)u) << 16; return x.f;
}
__device__ inline u16 f2bf(float f) {   // round-to-nearest-even
    union { float f; unsigned int i; } x; x.f = f;
    unsigned int r = x.i + 0x7FFFu + ((x.i >> 16) & 1u);
    return (u16)(r >> 16);
}

// ---- workspace layout (BYTE offsets), total ~103.0 MB ----
// h1   [N,128] bf16 @ 0          (25,600,000)
// hw1  [N, 96] bf16 @ 25,600,000 (19,200,000)
// h2   [N, 96] bf16 @ 44,800,000 (19,200,000)
// hw2  [N, 64] bf16 @ 64,000,000 (12,800,000)  (cols 54..63 are zero-pad)
// h3   [N, 64] bf16 @ 76,800,000 (12,800,000)
// ssrc [E] int      @ 89,600,000 ( 6,400,000)
// sw   [E] f32      @ 96,000,000 ( 6,400,000)
// off  [N] int      @102,400,000 (   400,000)
// bsum [392] int    @102,800,000 (     1,600)
// BpC  conv Bpack   @102,801,600 (    98,304)   [12][8][64][8] bf16
// Bp1  W1 Bpack     @102,899,904 (    24,576)   [4][6][64][8]
// Bp2  W2 Bpack     @102,924,480 (    12,288)   [3][4][64][8]
// cb   f32[128]     @102,936,768 (       512)
// hg   f32[64*150]  @102,937,280 (    38,400)

// ---------------------------------------------------------------------------
// Fold BN into conv weights + pack all weight matrices into MFMA fragment
// order: Bpack[ks][ct][lane][j] = B[k = ks*32 + (lane>>4)*8 + j][c = ct*16 + (lane&15)]
__global__ __launch_bounds__(256) void prep_pack(
        const float* __restrict__ conv_w, const float* __restrict__ conv_b,
        const float* __restrict__ gamma, const float* __restrict__ beta,
        const float* __restrict__ mean, const float* __restrict__ var,
        const float* __restrict__ W1, const float* __restrict__ W2,
        u16* __restrict__ BpC, u16* __restrict__ Bp1, u16* __restrict__ Bp2,
        float* __restrict__ cb) {
    int idx = blockIdx.x * 256 + threadIdx.x;   // 264*256 = 67,584 exact
    if (idx < 128) {
        float sc = gamma[idx] * rsqrtf(var[idx] + 1e-5f);
        cb[idx] = (conv_b[idx] - mean[idx]) * sc + beta[idx];
    }
    if (idx < 49152) {                      // conv: B[kk][o], kk = k*128+i
        int j = idx & 7, l = (idx >> 3) & 63;
        int ct = (idx >> 9) & 7, ks = idx >> 12;        // ks<12
        int kk = ks * 32 + (l >> 4) * 8 + j;
        int o  = ct * 16 + (l & 15);
        int k = kk >> 7, i = kk & 127;
        float sc = gamma[o] * rsqrtf(var[o] + 1e-5f);
        BpC[idx] = f2bf(conv_w[o * 384 + i * 3 + k] * sc);
    }
    int i1 = idx - 49152;
    if (i1 >= 0 && i1 < 12288) {            // W1 [128][96]
        int j = i1 & 7, l = (i1 >> 3) & 63;
        int rest = i1 >> 9; int ct = rest % 6, ks = rest / 6;   // ks<4
        int k = ks * 32 + (l >> 4) * 8 + j;
        int c = ct * 16 + (l & 15);
        Bp1[i1] = f2bf(W1[k * 96 + c]);
    }
    int i2 = idx - 61440;
    if (i2 >= 0 && i2 < 6144) {             // W2 [96][54] padded to 64 cols
        int j = i2 & 7, l = (i2 >> 3) & 63;
        int rest = i2 >> 9; int ct = rest & 3, ks = rest >> 2;  // ks<3
        int k = ks * 32 + (l >> 4) * 8 + j;
        int c = ct * 16 + (l & 15);
        Bp2[i2] = f2bf(c < 54 ? W2[k * 54 + c] : 0.f);
    }
}

// ---------------------------------------------------------------------------
// conv1d(k=3,pad=1)+BN+ReLU as MFMA GEMM, K=384 (kk=k*128+i).
// Block: 256 thr = 4 waves, 64 nodes; wave w: rows [n0+16w, +16) x 128 cols.
__global__ __launch_bounds__(256) void conv_mfma(
        const float* __restrict__ x, const u16* __restrict__ Bp,
        const float* __restrict__ bias, u16* __restrict__ h1) {
    __shared__ u16 xs[66][136];             // rows n0-1 .. n0+64, pitch-padded
    const int tid = threadIdx.x;
    const int n0 = blockIdx.x * 64;

    {   // stage 66 rows x 128 ch fp32 -> bf16
        int c4 = (tid & 31) * 4;
        int rr = tid >> 5;                  // 0..7
        for (int pass = 0; pass < 9; ++pass) {
            int r = rr + pass * 8;
            if (r < 66) {
                int n = n0 - 1 + r;
                float4 v = make_float4(0.f, 0.f, 0.f, 0.f);
                if (n >= 0 && n < NNODES) v = *(const float4*)&x[(size_t)n * 128 + c4];
                xs[r][c4 + 0] = f2bf(v.x);
                xs[r][c4 + 1] = f2bf(v.y);
                xs[r][c4 + 2] = f2bf(v.z);
                xs[r][c4 + 3] = f2bf(v.w);
            }
        }
    }
    __syncthreads();

    const int lane = tid & 63, w = tid >> 6;
    const int l15 = lane & 15, g = lane >> 4;
    f32x4 acc[8];
#pragma unroll
    for (int ct = 0; ct < 8; ++ct) acc[ct] = f32x4{0.f, 0.f, 0.f, 0.f};

    for (int ks = 0; ks < 12; ++ks) {
        int k = ks >> 2;                                // conv tap
        int icol = (ks & 3) * 32 + g * 8;               // in-channel base
        bf16x8 a = *(const bf16x8*)&xs[w * 16 + l15 + k][icol];
        const u16* bp = Bp + (((size_t)ks * 8) * 64 + lane) * 8;
#pragma unroll
        for (int ct = 0; ct < 8; ++ct) {
            bf16x8 b = *(const bf16x8*)(bp + (size_t)ct * 512);
            acc[ct] = __builtin_amdgcn_mfma_f32_16x16x32_bf16(a, b, acc[ct], 0, 0, 0);
        }
    }

#pragma unroll
    for (int ct = 0; ct < 8; ++ct) {
        int c = ct * 16 + l15;
        float bv = bias[c];
#pragma unroll
        for (int q = 0; q < 4; ++q) {
            int n = n0 + w * 16 + g * 4 + q;
            if (n < NNODES)
                h1[(size_t)n * 128 + c] = f2bf(fmaxf(acc[ct][q] + bv, 0.f));
        }
    }
}

// ---------------------------------------------------------------------------
// C[M,NOUT](bf16) = A[M,K](bf16) @ Bpack.  Block: 4 waves, 64 rows.
template <int K, int CT, int KS, int NOUT>
__global__ __launch_bounds__(256) void gemm_mfma(
        const u16* __restrict__ A, const u16* __restrict__ Bp, u16* __restrict__ C) {
    __shared__ u16 xs[64][K + 8];
    const int tid = threadIdx.x;
    const int n0 = blockIdx.x * 64;

    for (int ch = tid; ch < 64 * (K / 8); ch += 256) {
        int r = ch / (K / 8);
        int c8 = (ch % (K / 8)) * 8;
        int n = n0 + r;
        bf16x8 v{};
        if (n < NNODES) v = *(const bf16x8*)&A[(size_t)n * K + c8];
        *(bf16x8*)&xs[r][c8] = v;
    }
    __syncthreads();

    const int lane = tid & 63, w = tid >> 6;
    const int l15 = lane & 15, g = lane >> 4;
    f32x4 acc[CT];
#pragma unroll
    for (int ct = 0; ct < CT; ++ct) acc[ct] = f32x4{0.f, 0.f, 0.f, 0.f};

#pragma unroll
    for (int ks = 0; ks < KS; ++ks) {
        bf16x8 a = *(const bf16x8*)&xs[w * 16 + l15][ks * 32 + g * 8];
        const u16* bp = Bp + (((size_t)ks * CT) * 64 + lane) * 8;
#pragma unroll
        for (int ct = 0; ct < CT; ++ct) {
            bf16x8 b = *(const bf16x8*)(bp + (size_t)ct * 512);
            acc[ct] = __builtin_amdgcn_mfma_f32_16x16x32_bf16(a, b, acc[ct], 0, 0, 0);
        }
    }

#pragma unroll
    for (int ct = 0; ct < CT; ++ct) {
        int c = ct * 16 + l15;
#pragma unroll
        for (int q = 0; q < 4; ++q) {
            int n = n0 + w * 16 + g * 4 + q;
            if (n < NNODES) C[(size_t)n * NOUT + c] = f2bf(acc[ct][q]);
        }
    }
}

// ---------------------------------------------------------------------------
// CSR-by-dst build: histogram -> 3-phase hierarchical exclusive scan -> fill.
__global__ void edge_count(const int* __restrict__ dst, int* __restrict__ off) {
    int e = blockIdx.x * 256 + threadIdx.x;
    if (e < NEDGES) atomicAdd(&off[dst[e]], 1);
}

__global__ __launch_bounds__(256) void scan_block(int* __restrict__ off, int* __restrict__ bsum) {
    __shared__ int s[256];
    const int t = threadIdx.x;
    const int idx = blockIdx.x * 256 + t;
    int v = (idx < NNODES) ? off[idx] : 0;
    s[t] = v;
    __syncthreads();
    for (int d = 1; d < 256; d <<= 1) {
        int add = (t >= d) ? s[t - d] : 0;
        __syncthreads();
        s[t] += add;
        __syncthreads();
    }
    if (idx < NNODES) off[idx] = s[t] - v;
    if (t == 255) bsum[blockIdx.x] = s[255];
}

__global__ __launch_bounds__(512) void scan_bsum(int* __restrict__ bsum) {
    __shared__ int s[512];
    const int t = threadIdx.x;
    int v = (t < 392) ? bsum[t] : 0;
    s[t] = v;
    __syncthreads();
    for (int d = 1; d < 512; d <<= 1) {
        int add = (t >= d) ? s[t - d] : 0;
        __syncthreads();
        s[t] += add;
        __syncthreads();
    }
    if (t < 392) bsum[t] = s[t] - v;
}

__global__ __launch_bounds__(256) void scan_add(int* __restrict__ off, const int* __restrict__ bsum) {
    int idx = blockIdx.x * 256 + threadIdx.x;
    if (idx < NNODES) off[idx] += bsum[blockIdx.x];
}

__global__ void edge_fill(const int* __restrict__ src, const int* __restrict__ dst,
                          const float* __restrict__ ew, int* __restrict__ off,
                          int* __restrict__ ssrc, float* __restrict__ sw) {
    int e = blockIdx.x * 256 + threadIdx.x;
    if (e >= NEDGES) return;
    int d = dst[e];
    int pos = atomicAdd(&off[d], 1);
    ssrc[pos] = src[e];
    sw[pos] = ew[e];
}

// ---------------------------------------------------------------------------
// Gather-aggregate + bias + ReLU (bf16 in/out, fp32 accum).
// 96 ch: thread = (node, 16B chunk p<12).
__global__ __launch_bounds__(256) void gather_96(
        const int* __restrict__ off, const int* __restrict__ ssrc,
        const float* __restrict__ sw, const u16* __restrict__ hw,
        const float* __restrict__ bias, u16* __restrict__ out) {
    int gid = blockIdx.x * 256 + threadIdx.x;
    if (gid >= NNODES * 12) return;
    int n = gid / 12, p = gid - n * 12;
    int s0 = n ? off[n - 1] : 0, e1 = off[n];
    float acc[8] = {0.f, 0.f, 0.f, 0.f, 0.f, 0.f, 0.f, 0.f};
    for (int e = s0; e < e1; ++e) {
        int s = ssrc[e];
        float w = sw[e];
        bf16x8 v = *(const bf16x8*)&hw[(size_t)s * 96 + p * 8];
#pragma unroll
        for (int j = 0; j < 8; ++j) acc[j] += w * bf2f((u16)v[j]);
    }
    u16 r[8];
#pragma unroll
    for (int j = 0; j < 8; ++j) r[j] = f2bf(fmaxf(acc[j] + bias[p * 8 + j], 0.f));
    *(bf16x8*)&out[(size_t)n * 96 + p * 8] = *(bf16x8*)r;
}

// 64-wide (54 valid): thread = (node, 16B chunk p<8).
__global__ __launch_bounds__(256) void gather_64(
        const int* __restrict__ off, const int* __restrict__ ssrc,
        const float* __restrict__ sw, const u16* __restrict__ hw,
        const float* __restrict__ bias, u16* __restrict__ out) {
    int gid = blockIdx.x * 256 + threadIdx.x;
    if (gid >= NNODES * 8) return;
    int n = gid / 8, p = gid - n * 8;
    int s0 = n ? off[n - 1] : 0, e1 = off[n];
    float acc[8] = {0.f, 0.f, 0.f, 0.f, 0.f, 0.f, 0.f, 0.f};
    for (int e = s0; e < e1; ++e) {
        int s = ssrc[e];
        float w = sw[e];
        bf16x8 v = *(const bf16x8*)&hw[(size_t)s * 64 + p * 8];
#pragma unroll
        for (int j = 0; j < 8; ++j) acc[j] += w * bf2f((u16)v[j]);
    }
    u16 r[8];
#pragma unroll
    for (int j = 0; j < 8; ++j) {
        int c = p * 8 + j;
        float bv = (c < 54) ? bias[c] : 0.f;
        r[j] = f2bf(fmaxf(acc[j] + bv, 0.f));
    }
    *(bf16x8*)&out[(size_t)n * 64 + p * 8] = *(bf16x8*)r;
}

// ---------------------------------------------------------------------------
// Pooling over sorted graph_ids: block = ~49-node range, thread = channel.
// 2048 blocks for latency hiding; flush atomics only at graph boundaries.
__global__ __launch_bounds__(192) void pool_kernel(
        const u16* __restrict__ h2, const u16* __restrict__ h3,
        const int* __restrict__ gids, float* __restrict__ hg) {
    const int c = threadIdx.x;
    const int chunk = (NNODES + gridDim.x - 1) / gridDim.x;
    const int n0 = blockIdx.x * chunk;
    const int n1 = min(n0 + chunk, NNODES);
    if (c >= 150 || n0 >= NNODES) return;
    float acc = 0.f;
    int g = gids[n0];
    for (int n = n0; n < n1; ++n) {
        int gn = gids[n];
        if (gn != g) {
            atomicAdd(&hg[g * 150 + c], acc);
            acc = 0.f;
            g = gn;
        }
        acc += (c < 96) ? bf2f(h2[(size_t)n * 96 + c]) : bf2f(h3[(size_t)n * 64 + (c - 96)]);
    }
    atomicAdd(&hg[g * 150 + c], acc);
}

__global__ __launch_bounds__(320) void final_kernel(
        const float* __restrict__ hg, const float* __restrict__ Wc,
        const float* __restrict__ bc, float* __restrict__ out) {
    int tid = threadIdx.x;
    int g = tid / 5, o = tid - g * 5;
    float s = bc[o];
    for (int c = 0; c < 150; ++c) s += hg[g * 150 + c] * Wc[o * 150 + c];
    out[g * 5 + o] = s;
}

// ---------------------------------------------------------------------------
extern "C" void kernel_launch(void* const* d_in, const int* in_sizes, int n_in,
                              void* d_out, int out_size, void* d_ws, size_t ws_size,
                              hipStream_t stream) {
    const float* node_feats = (const float*)d_in[0];
    const float* edge_w     = (const float*)d_in[1];
    const int*   src        = (const int*)d_in[2];
    const int*   dst        = (const int*)d_in[3];
    const int*   gids       = (const int*)d_in[4];
    const float* conv_w     = (const float*)d_in[5];
    const float* conv_b     = (const float*)d_in[6];
    const float* bn_gamma   = (const float*)d_in[7];
    const float* bn_beta    = (const float*)d_in[8];
    const float* bn_mean    = (const float*)d_in[9];
    const float* bn_var     = (const float*)d_in[10];
    const float* W1         = (const float*)d_in[11];
    const float* b1         = (const float*)d_in[12];
    const float* W2         = (const float*)d_in[13];
    const float* b2         = (const float*)d_in[14];
    const float* Wc         = (const float*)d_in[15];
    const float* bc         = (const float*)d_in[16];

    char* W = (char*)d_ws;
    u16*   h1   = (u16*)(W + 0);
    u16*   hw1  = (u16*)(W + 25600000);
    u16*   h2   = (u16*)(W + 44800000);
    u16*   hw2  = (u16*)(W + 64000000);
    u16*   h3   = (u16*)(W + 76800000);
    int*   ssrc = (int*)(W + 89600000);
    float* sw   = (float*)(W + 96000000);
    int*   off  = (int*)(W + 102400000);
    int*   bsum = (int*)(W + 102800000);
    u16*   BpC  = (u16*)(W + 102801600);
    u16*   Bp1  = (u16*)(W + 102899904);
    u16*   Bp2  = (u16*)(W + 102924480);
    float* cb   = (float*)(W + 102936768);
    float* hg   = (float*)(W + 102937280);
    float* out  = (float*)d_out;

    // 1. fold BN + pack weights into MFMA fragment order
    prep_pack<<<264, 256, 0, stream>>>(conv_w, conv_b, bn_gamma, bn_beta,
                                       bn_mean, bn_var, W1, W2, BpC, Bp1, Bp2, cb);
    // 2. conv+BN+ReLU (MFMA) -> h1 bf16 [N,128]
    conv_mfma<<<1563, 256, 0, stream>>>(node_feats, BpC, cb, h1);
    // 3. hw1 = h1 @ W1 (MFMA) -> bf16 [N,96]
    gemm_mfma<128, 6, 4, 96><<<1563, 256, 0, stream>>>(h1, Bp1, hw1);
    // 4. build CSR by dst
    hipMemsetAsync(off, 0, NNODES * sizeof(int), stream);
    edge_count<<<6250, 256, 0, stream>>>(dst, off);
    scan_block<<<392, 256, 0, stream>>>(off, bsum);
    scan_bsum<<<1, 512, 0, stream>>>(bsum);
    scan_add<<<392, 256, 0, stream>>>(off, bsum);
    edge_fill<<<6250, 256, 0, stream>>>(src, dst, edge_w, off, ssrc, sw);
    // 5. h2 = relu(gather(hw1) + b1)  bf16 [N,96]
    gather_96<<<4688, 256, 0, stream>>>(off, ssrc, sw, hw1, b1, h2);
    // 6. hw2 = h2 @ W2 (MFMA) -> bf16 [N,64] (54 valid, pad zero)
    gemm_mfma<96, 4, 3, 64><<<1563, 256, 0, stream>>>(h2, Bp2, hw2);
    // 7. h3 = relu(gather(hw2) + b2)  bf16 [N,64]
    gather_64<<<3125, 256, 0, stream>>>(off, ssrc, sw, hw2, b2, h3);
    // 8. pooling (2048 blocks; ~49 nodes/block)
    hipMemsetAsync(hg, 0, (size_t)NGRAPHS * 150 * sizeof(float), stream);
    pool_kernel<<<POOL_BLOCKS, 192, 0, stream>>>(h2, h3, gids, hg);
    // 9. final linear
    final_kernel<<<1, 320, 0, stream>>>(hg, Wc, bc, out);
}